// Round 12
// baseline (2392.640 us; speedup 1.0000x reference)
//
#include <hip/hip_runtime.h>
#include <hip/hip_bf16.h>
#include <math.h>

// Problem constants
#define Bd 8
#define Nd 1024
#define Hd 200
#define HP 224                      // Hd padded to multiple of 32
#define BN (Bd*Nd)                  // 8192
#define SZ_BNH ((size_t)BN*Hd)      // 1,638,400
#define SZ_BNN ((size_t)BN*Nd)      // 8,388,608
#define SZ_PAD ((size_t)BN*HP)      // 1,835,008

typedef __hip_bfloat16 bf16;
typedef __attribute__((ext_vector_type(8))) short bf16x8;   // 8 bf16 = 4 VGPRs (A/B frag)
typedef __attribute__((ext_vector_type(4))) float f32x4;    // C/D frag

__device__ __forceinline__ float bf2f(bf16 v){ return __bfloat162float(v); }
__device__ __forceinline__ bf16 f2bf(float v){ return __float2bfloat16(v); }

#define MFMA16(a,b,c) __builtin_amdgcn_mfma_f32_16x16x32_bf16((a),(b),(c),0,0,0)

// ============================ prep (fp32) ============================
__global__ void k_prep_masks(const float* __restrict__ tm, float* __restrict__ maskf,
                             float* __restrict__ maskadd){
  int i = blockIdx.x*256 + threadIdx.x;
  if (i < BN){ float m = tm[i]; maskf[i] = m; maskadd[i] = (1.f - m) * -10000.f; }
}

__global__ void k_prep_adj(const float* __restrict__ a1, const float* __restrict__ a2,
                           float* __restrict__ adj_out, float* __restrict__ denom){
  int r = blockIdx.x;
  const size_t base = (size_t)r * Nd;
  int t = threadIdx.x;
  float s = 0.f;
  for (int m = t; m < Nd; m += 256){
    float a = a1[base+m] + a2[base+m];
    a = a >= 1.f ? 1.f : a;
    adj_out[base+m] = a;
    s += a;
  }
  __shared__ float red[256];
  red[t] = s; __syncthreads();
  for (int st = 128; st > 0; st >>= 1){ if (t < st) red[t] += red[t+st]; __syncthreads(); }
  if (t == 0) denom[r] = red[0] + 1e-07f;
}

__global__ void k_copy2(const float* __restrict__ x, float* __restrict__ o1,
                        float* __restrict__ o2){
  size_t i = (size_t)blockIdx.x*256 + threadIdx.x;
  if (i < SZ_BNH){ float v = x[i]; o1[i] = v; o2[i] = v; }
}

// ============================ split conversions ============================
__global__ void c_pad_split(const float* __restrict__ X, bf16* __restrict__ Oh,
                            bf16* __restrict__ Ol){
  size_t i = (size_t)blockIdx.x*256 + threadIdx.x;
  if (i >= SZ_PAD) return;
  int c = (int)(i % HP); size_t r = i / HP;
  float v = (c < Hd) ? X[r*Hd + c] : 0.f;
  bf16 h = f2bf(v);
  Oh[i] = h; Ol[i] = f2bf(v - bf2f(h));
}

__global__ void c_padT_split(const float* __restrict__ X, bf16* __restrict__ Oh,
                             bf16* __restrict__ Ol){
  __shared__ float t[32][33];
  int b = blockIdx.z, m0 = blockIdx.x*32, d0 = blockIdx.y*32;
  int tx = threadIdx.x, ty = threadIdx.y;          // block (32,8)
  for (int i = ty; i < 32; i += 8){
    int d = d0 + tx;
    t[i][tx] = (d < Hd) ? X[((size_t)b*Nd + m0+i)*Hd + d] : 0.f;
  }
  __syncthreads();
  for (int i = ty; i < 32; i += 8){
    size_t idx = (size_t)b*HP*Nd + (size_t)(d0+i)*Nd + m0 + tx;
    float v = t[tx][i];
    bf16 h = f2bf(v);
    Oh[idx] = h; Ol[idx] = f2bf(v - bf2f(h));
  }
}

__global__ void c_w_split(const float* __restrict__ W, bf16* __restrict__ Oh,
                          bf16* __restrict__ Ol){
  int i = blockIdx.x*256 + threadIdx.x;
  if (i >= HP*HP) return;
  int n = i / HP, k = i % HP;
  float v = (n < Hd && k < Hd) ? W[k*Hd + n] : 0.f;
  bf16 h = f2bf(v);
  Oh[i] = h; Ol[i] = f2bf(v - bf2f(h));
}

__global__ void c_cvt1024(const float* __restrict__ X, bf16* __restrict__ O){
  size_t i = (size_t)blockIdx.x*256 + threadIdx.x;
  if (i < SZ_BNN) O[i] = f2bf(X[i]);
}

// attention probs: single bf16 (coalesced, exp once per element)
__global__ void c_prow(const float* __restrict__ S, const float* __restrict__ rmax,
                       const float* __restrict__ rsum, bf16* __restrict__ P){
  size_t i = (size_t)blockIdx.x*256 + threadIdx.x;
  if (i >= SZ_BNN) return;
  size_t r = i >> 10;
  P[i] = f2bf(expf(S[i] - rmax[r]) * (1.f / rsum[r]));
}

// alignment p_row: Dekker split pair
__global__ void c_prow_split(const float* __restrict__ S, const float* __restrict__ rmax,
                             const float* __restrict__ rsum, bf16* __restrict__ Ph,
                             bf16* __restrict__ Pl){
  size_t i = (size_t)blockIdx.x*256 + threadIdx.x;
  if (i >= SZ_BNN) return;
  size_t r = i >> 10;
  float p = expf(S[i] - rmax[r]) * (1.f / rsum[r]);
  bf16 h = f2bf(p);
  Ph[i] = h; Pl[i] = f2bf(p - bf2f(h));
}

__global__ void c_pcolT_split(const float* __restrict__ S, const float* __restrict__ cmax,
                              const float* __restrict__ csum, bf16* __restrict__ Ph,
                              bf16* __restrict__ Pl){
  __shared__ float t[32][33];
  int b = blockIdx.z, n0 = blockIdx.x*32, m0 = blockIdx.y*32;
  int tx = threadIdx.x, ty = threadIdx.y;          // block (32,8)
  for (int i = ty; i < 32; i += 8)
    t[i][tx] = S[(size_t)b*Nd*Nd + (size_t)(n0+i)*Nd + m0 + tx];
  __syncthreads();
  for (int i = ty; i < 32; i += 8){
    int m = m0 + i;
    float cm = cmax[b*Nd + m], ci = 1.f / csum[b*Nd + m];
    float p = expf(t[tx][i] - cm) * ci;
    size_t idx = (size_t)b*Nd*Nd + (size_t)m*Nd + n0 + tx;
    bf16 h = f2bf(p);
    Ph[idx] = h; Pl[idx] = f2bf(p - bf2f(h));
  }
}

// ============================ softmax stats (fp32) ============================
__global__ void k_rowstats(const float* __restrict__ S, float* __restrict__ rmax,
                           float* __restrict__ rsum){
  size_t r = blockIdx.x;
  const float* row = S + r*Nd;
  int t = threadIdx.x;
  __shared__ float red[256];
  float mx = -3.4e38f;
  for (int i = t; i < Nd; i += 256) mx = fmaxf(mx, row[i]);
  red[t] = mx; __syncthreads();
  for (int s = 128; s > 0; s >>= 1){ if (t < s) red[t] = fmaxf(red[t], red[t+s]); __syncthreads(); }
  mx = red[0]; __syncthreads();
  float sum = 0.f;
  for (int i = t; i < Nd; i += 256) sum += expf(row[i] - mx);
  red[t] = sum; __syncthreads();
  for (int s = 128; s > 0; s >>= 1){ if (t < s) red[t] += red[t+s]; __syncthreads(); }
  if (t == 0){ rmax[r] = mx; rsum[r] = red[0]; }
}

// Single-pass online column softmax stats. 1024 threads: 64 cols x 16 row-groups.
__global__ __launch_bounds__(1024)
void k_colstats(const float* __restrict__ S, float* __restrict__ cmax,
                float* __restrict__ csum){
  int b = blockIdx.y;
  int tx = threadIdx.x & 63, ty = threadIdx.x >> 6;   // ty in 0..15
  int m = blockIdx.x*64 + tx;
  const float* Sbp = S + (size_t)b*Nd*Nd + m;
  float mx = -3.4e38f, sm = 0.f;
  for (int n = ty; n < Nd; n += 16){
    float x = Sbp[(size_t)n*Nd];
    if (x > mx){ sm = sm * expf(mx - x) + 1.f; mx = x; }
    else        sm += expf(x - mx);
  }
  __shared__ float smx[16][64], ssm[16][64];
  smx[ty][tx] = mx; ssm[ty][tx] = sm;
  __syncthreads();
  for (int st = 8; st > 0; st >>= 1){
    if (ty < st){
      float m1 = smx[ty][tx],    s1 = ssm[ty][tx];
      float m2 = smx[ty+st][tx], s2 = ssm[ty+st][tx];
      float M = fmaxf(m1, m2);
      smx[ty][tx] = M;
      ssm[ty][tx] = s1*expf(m1 - M) + s2*expf(m2 - M);
    }
    __syncthreads();
  }
  if (ty == 0){ cmax[b*Nd + m] = smx[0][tx]; csum[b*Nd + m] = ssm[0][tx]; }
}

// ============================ residual + layernorm ============================
__global__ void k_add_ln(const float* __restrict__ X, const float* __restrict__ R,
                         const float* __restrict__ g, const float* __restrict__ bb,
                         float* __restrict__ Y){
  int r = blockIdx.x, t = threadIdx.x;
  __shared__ float red[256];
  bool act = t < Hd;
  float v = 0.f;
  if (act) v = X[(size_t)r*Hd + t] + R[(size_t)r*Hd + t];
  red[t] = act ? v : 0.f; __syncthreads();
  for (int s = 128; s > 0; s >>= 1){ if (t < s) red[t] += red[t+s]; __syncthreads(); }
  float mu = red[0] * (1.f/Hd); __syncthreads();
  float d = act ? (v - mu) : 0.f;
  red[t] = d*d; __syncthreads();
  for (int s = 128; s > 0; s >>= 1){ if (t < s) red[t] += red[t+s]; __syncthreads(); }
  float var = red[0] * (1.f/Hd);
  if (act){
    float rs = 1.f / sqrtf(var + 1e-20f);
    Y[(size_t)r*Hd + t] = (v - mu) * rs * g[t] + bb[t];
  }
}

__global__ void k_store(const float* __restrict__ X, float* __restrict__ O){
  size_t i = (size_t)blockIdx.x*256 + threadIdx.x;
  if (i < SZ_BNH) O[i] = X[i];
}

// ============================ split-precision MFMA GEMM (no split-K) ============
// D[m][n] = sum_k A[m][k]*B[n][k] (NT), Dekker split. RI row-tiles x CJ col-tiles/wave.
// Block = 4 waves stacked in M. EPI: 0 fp32 Y=acc+bias  1 +gelu  2 split-bf16pad out
// 3 S=acc*scale+maskadd[col]  4 S=acc+pairmask
template<int EPI, int TERMS, int RI, int CJ>
__global__ __launch_bounds__(256)
void k_mfma3(const bf16* __restrict__ Ah, const bf16* __restrict__ Al,
             const bf16* __restrict__ Bh, const bf16* __restrict__ Bl,
             float* __restrict__ Y, bf16* __restrict__ Ybh, bf16* __restrict__ Ybl,
             const float* __restrict__ bias, const float* __restrict__ e0,
             const float* __restrict__ e1,
             int Kp, size_t sAb, size_t sBb, float scale)
{
  int b = blockIdx.z;
  int wave = threadIdx.x >> 6, lane = threadIdx.x & 63;
  int r0 = (blockIdx.y*4 + wave)*(RI*16);
  int c0 = blockIdx.x*(CJ*16);
  int lm = lane & 15, lq = lane >> 4;
  size_t a0 = (size_t)b*sAb + (size_t)(r0+lm)*Kp + lq*8;
  size_t bo = (size_t)b*sBb + (size_t)(c0+lm)*Kp + lq*8;

  f32x4 acc[RI][CJ] = {};
  for (int k = 0; k < Kp; k += 32){
    bf16x8 ah[RI], bh[CJ], bl[CJ];
    #pragma unroll
    for (int i = 0; i < RI; i++) ah[i] = *(const bf16x8*)(Ah + a0 + (size_t)(i*16)*Kp + k);
    #pragma unroll
    for (int j = 0; j < CJ; j++){
      bh[j] = *(const bf16x8*)(Bh + bo + (size_t)(j*16)*Kp + k);
      bl[j] = *(const bf16x8*)(Bl + bo + (size_t)(j*16)*Kp + k);
    }
    #pragma unroll
    for (int i = 0; i < RI; i++)
      #pragma unroll
      for (int j = 0; j < CJ; j++) acc[i][j] = MFMA16(ah[i], bh[j], acc[i][j]);
    #pragma unroll
    for (int i = 0; i < RI; i++)
      #pragma unroll
      for (int j = 0; j < CJ; j++) acc[i][j] = MFMA16(ah[i], bl[j], acc[i][j]);
    if (TERMS >= 3){
      bf16x8 al[RI];
      #pragma unroll
      for (int i = 0; i < RI; i++) al[i] = *(const bf16x8*)(Al + a0 + (size_t)(i*16)*Kp + k);
      #pragma unroll
      for (int i = 0; i < RI; i++)
        #pragma unroll
        for (int j = 0; j < CJ; j++) acc[i][j] = MFMA16(al[i], bh[j], acc[i][j]);
    }
  }

  #pragma unroll
  for (int i = 0; i < RI; i++){
    #pragma unroll
    for (int j = 0; j < CJ; j++){
      int col = c0 + j*16 + lm;
      int rbase = r0 + i*16 + lq*4;
      #pragma unroll
      for (int r = 0; r < 4; r++){
        int row = rbase + r;
        size_t rowg = (size_t)b*Nd + row;
        float v = acc[i][j][r];
        if (EPI == 0 || EPI == 1){
          if (col < Hd){
            v += bias ? bias[col] : 0.f;
            if (EPI == 1) v = 0.5f*v*(1.f + erff(v*0.7071067811865476f));
            Y[rowg*Hd + col] = v;
          }
        } else if (EPI == 2){
          if (col < HP){
            float o = (col < Hd) ? v + (bias ? bias[col] : 0.f) : 0.f;
            bf16 h = f2bf(o);
            Ybh[rowg*HP + col] = h;
            Ybl[rowg*HP + col] = f2bf(o - bf2f(h));
          }
        } else if (EPI == 3){
          Y[rowg*Nd + col] = v*scale + e0[b*Nd + col];
        } else if (EPI == 4){
          Y[rowg*Nd + col] = v + (1.f - e1[b*Nd+row]*e1[b*Nd+col])*(-10000.f);
        }
      }
    }
  }
}

// ============================ split-K=4 MFMA GEMM (K=1024 mixes) ================
// Block = one 16x64 tile; 4 waves each own a K/4 chunk; LDS combine (fixed order
// red[0]+red[1]+red[2]+red[3] — bitwise identical to previous rounds); wave j
// epilogues col-tile j over all 16 rows.
// XCD swizzle: blockIdx.x = row-tile (64), blockIdx.y = col-group (4) — the 4
// col-group blocks sharing an A-tile are stride-64 apart in linear block ID,
// landing on the SAME XCD (64 % 8 == 0) so A re-reads hit local L2.
// EPI: 0 Y=acc  5 Y+=relu(acc/denom[row])  6 Y=acc*maskf[row]+R  7 Y=acc*maskf[row]+Y
template<int EPI, int TERMS>
__global__ __launch_bounds__(256)
void k_mfma3sk(const bf16* __restrict__ Ah, const bf16* __restrict__ Al,
               const bf16* __restrict__ Bh, const bf16* __restrict__ Bl,
               float* __restrict__ Y, const float* __restrict__ e0,
               const float* __restrict__ e1, const float* __restrict__ R,
               int Kp, size_t sAb, size_t sBb)
{
  __shared__ float red[4][64][17];
  int b = blockIdx.z;
  int wave = threadIdx.x >> 6, lane = threadIdx.x & 63;
  int r0 = blockIdx.x*16;
  int c0 = blockIdx.y*64;
  int lm = lane & 15, lq = lane >> 4;
  size_t a0 = (size_t)b*sAb + (size_t)(r0+lm)*Kp + lq*8;
  size_t bo = (size_t)b*sBb + (size_t)(c0+lm)*Kp + lq*8;
  int kb = wave*(Kp>>2), ke = kb + (Kp>>2);

  f32x4 acc[4] = {};
  for (int k = kb; k < ke; k += 32){
    bf16x8 ah, bh[4], bl[4];
    ah = *(const bf16x8*)(Ah + a0 + k);
    #pragma unroll
    for (int j = 0; j < 4; j++){
      bh[j] = *(const bf16x8*)(Bh + bo + (size_t)(j*16)*Kp + k);
      bl[j] = *(const bf16x8*)(Bl + bo + (size_t)(j*16)*Kp + k);
    }
    #pragma unroll
    for (int j = 0; j < 4; j++) acc[j] = MFMA16(ah, bh[j], acc[j]);
    #pragma unroll
    for (int j = 0; j < 4; j++) acc[j] = MFMA16(ah, bl[j], acc[j]);
    if (TERMS >= 3){
      bf16x8 al = *(const bf16x8*)(Al + a0 + k);
      #pragma unroll
      for (int j = 0; j < 4; j++) acc[j] = MFMA16(al, bh[j], acc[j]);
    }
  }

  #pragma unroll
  for (int j = 0; j < 4; j++)
    #pragma unroll
    for (int r = 0; r < 4; r++)
      red[wave][lane][j*4 + r] = acc[j][r];
  __syncthreads();

  int j = wave;
  int col = c0 + j*16 + lm;
  #pragma unroll
  for (int r = 0; r < 4; r++){
    int f = j*4 + r;
    float v = red[0][lane][f] + red[1][lane][f] + red[2][lane][f] + red[3][lane][f];
    int row = r0 + lq*4 + r;
    size_t rowg = (size_t)b*Nd + row;
    if (EPI == 0){
      if (col < Hd) Y[rowg*Hd + col] = v;
    } else if (EPI == 5){
      if (col < Hd){
        float u = v / e0[b*Nd+row]; u = u > 0.f ? u : 0.f;
        Y[rowg*Hd + col] += u;
      }
    } else if (EPI == 6){
      if (col < Hd) Y[rowg*Hd+col] = v*e1[b*Nd+row] + R[rowg*Hd+col];
    } else if (EPI == 7){
      if (col < Hd) Y[rowg*Hd+col] = v*e1[b*Nd+row] + Y[rowg*Hd+col];
    }
  }
}

// ============================ host launch ============================
static inline char* carve(char*& p, size_t bytes){
  char* r = p;
  p += (bytes + 511) & ~(size_t)511;
  return r;
}

extern "C" void kernel_launch(void* const* d_in, const int* in_sizes, int n_in,
                              void* d_out, int out_size, void* d_ws, size_t ws_size,
                              hipStream_t stream){
  (void)in_sizes; (void)n_in; (void)out_size; (void)ws_size;
  const float* text     = (const float*)d_in[0];
  const float* adj1     = (const float*)d_in[1];
  const float* adj2     = (const float*)d_in[2];
  const float* textmask = (const float*)d_in[5];
  const float* gcn_w    = (const float*)d_in[6];
  const float* mut_w    = (const float*)d_in[7];
  const float* qw = (const float*)d_in[8],  *qb = (const float*)d_in[9];
  const float* kw = (const float*)d_in[10], *kb = (const float*)d_in[11];
  const float* vw = (const float*)d_in[12], *vb = (const float*)d_in[13];
  const float* aow= (const float*)d_in[14], *aob= (const float*)d_in[15];
  const float* g1 = (const float*)d_in[16], *b1 = (const float*)d_in[17];
  const float* iw = (const float*)d_in[18], *ib = (const float*)d_in[19];
  const float* ow = (const float*)d_in[20], *ob = (const float*)d_in[21];
  const float* g2 = (const float*)d_in[22], *b2 = (const float*)d_in[23];

  float* out_outs = (float*)d_out;
  float* out_adj  = out_outs + SZ_BNH;

  // ---- workspace carve (~109 MB). out_outs doubles as fp32 scratch sc2. ----
  char* p = (char*)d_ws;
  float* cur  = (float*)carve(p, SZ_BNH*4);
  float* sc1  = (float*)carve(p, SZ_BNH*4);
  float* fo   = (float*)carve(p, SZ_BNH*4);
  float* S    = (float*)carve(p, SZ_BNN*4);           // fp32 scores / logits
  bf16*  Rb   = (bf16*)carve(p, SZ_BNN*2*2);          // big bf16 region (33.6 MB)
  bf16*  T1   = (bf16*)carve(p, SZ_PAD*2);
  bf16*  T2   = (bf16*)carve(p, SZ_PAD*2);
  bf16*  T3   = (bf16*)carve(p, SZ_PAD*2);
  bf16*  T4   = (bf16*)carve(p, SZ_PAD*2);
  bf16*  T5   = (bf16*)carve(p, SZ_PAD*2);
  bf16*  T6   = (bf16*)carve(p, SZ_PAD*2);
  bf16*  Wh   = (bf16*)carve(p, (size_t)HP*HP*2);
  bf16*  Wl   = (bf16*)carve(p, (size_t)HP*HP*2);
  float* denom   = (float*)carve(p, BN*4);
  float* maskf   = (float*)carve(p, BN*4);
  float* maskadd = (float*)carve(p, BN*4);
  float* rmaxv   = (float*)carve(p, BN*4);
  float* rsumv   = (float*)carve(p, BN*4);
  float* cmaxv   = (float*)carve(p, BN*4);
  float* csumv   = (float*)carve(p, BN*4);

  float* sc2 = out_outs;          // fp32 scratch; overwritten by final k_store
  bf16* attnP = Rb;               // phases: attnP -> adjb -> p_row Ph/Pl -> p_col Ph/Pl
  bf16* adjb  = Rb;
  bf16* Ph    = Rb;
  bf16* Pl    = Rb + SZ_BNN;

  const size_t sNT = (size_t)Nd*HP;     // batch stride, [1024][224]
  const size_t sT  = (size_t)HP*Nd;     // batch stride, [224][1024]
  const size_t sNN = (size_t)Nd*Nd;     // batch stride, [1024][1024]

  dim3 blk256(256);
  dim3 gPad((unsigned)((SZ_PAD+255)/256));
  dim3 gPadT(32, 7, Bd), bT(32, 8);
  dim3 gPcolT(32, 32, Bd);
  dim3 gW((HP*HP+255)/256);
  dim3 gNNel((unsigned)((SZ_BNN+255)/256));
  dim3 gBNH((unsigned)((SZ_BNH+255)/256));
  // GEMM grids
  dim3 gSm(7, 128, 1);       // small GEMM: 16x32/wave (CJ=2), 8192 rows, cols 0..223
  dim3 gNT(16, 16, Bd);      // scores/logits: 16x64/wave (RI=1), 8192 waves
  dim3 gSK(64, 4, Bd);       // split-K=4 mixes: 16-row blocks, x=row-tile, y=col-group
  const float inv_sqrt_h = 0.07071067811865475f;  // 1/sqrt(200)
  const size_t Z = 0;

  k_prep_masks<<<(BN+255)/256, blk256, 0, stream>>>(textmask, maskf, maskadd);
  k_prep_adj<<<BN, blk256, 0, stream>>>(adj1, adj2, out_adj, denom);
  k_copy2<<<gBNH, blk256, 0, stream>>>(text, cur, fo);

  for (int i = 0; i < 3; i++){
    const float *qwi = qw + i*Hd*Hd, *qbi = qb + i*Hd;
    const float *kwi = kw + i*Hd*Hd, *kbi = kb + i*Hd;
    const float *vwi = vw + i*Hd*Hd, *vbi = vb + i*Hd;
    const float *aowi= aow+ i*Hd*Hd, *aobi= aob+ i*Hd;
    const float *g1i = g1 + i*Hd,    *b1i = b1 + i*Hd;
    const float *iwi = iw + i*Hd*Hd, *ibi = ib + i*Hd;
    const float *owi = ow + i*Hd*Hd, *obi = ob + i*Hd;
    const float *g2i = g2 + i*Hd,    *b2i = b2 + i*Hd;

    // ================= BERT layer: cur -> cur =================
    c_pad_split<<<gPad, blk256, 0, stream>>>(cur, T1, T2);                  // cur pair
    c_w_split<<<gW, blk256, 0, stream>>>(qwi, Wh, Wl);
    k_mfma3<2,3,1,2><<<gSm, blk256, 0, stream>>>(T1,T2,Wh,Wl, nullptr,T3,T4,
              qbi, nullptr,nullptr, HP, Z,Z, 0.f);                          // Q pair
    c_w_split<<<gW, blk256, 0, stream>>>(kwi, Wh, Wl);
    k_mfma3<2,3,1,2><<<gSm, blk256, 0, stream>>>(T1,T2,Wh,Wl, nullptr,T5,T6,
              kbi, nullptr,nullptr, HP, Z,Z, 0.f);                          // K pair
    k_mfma3<3,3,1,4><<<gNT, blk256, 0, stream>>>(T3,T4,T5,T6, S,nullptr,nullptr,
              nullptr, maskadd,nullptr, HP, sNT,sNT, inv_sqrt_h);           // scores
    c_w_split<<<gW, blk256, 0, stream>>>(vwi, Wh, Wl);
    k_mfma3<0,3,1,2><<<gSm, blk256, 0, stream>>>(T1,T2,Wh,Wl, sc1,nullptr,nullptr,
              vbi, nullptr,nullptr, HP, Z,Z, 0.f);                          // V fp32
    k_rowstats<<<BN, blk256, 0, stream>>>(S, rmaxv, rsumv);
    c_prow<<<gNNel, blk256, 0, stream>>>(S, rmaxv, rsumv, attnP);           // attn probs (single)
    c_padT_split<<<gPadT, bT, 0, stream>>>(sc1, T1, T2);                    // V^T pair
    k_mfma3sk<0,2><<<gSK, blk256, 0, stream>>>(attnP,nullptr,T1,T2,
              sc2, nullptr,nullptr,nullptr, Nd, sNN,sT);                    // ctx
    c_pad_split<<<gPad, blk256, 0, stream>>>(sc2, T3, T4);
    c_w_split<<<gW, blk256, 0, stream>>>(aowi, Wh, Wl);
    k_mfma3<0,3,1,2><<<gSm, blk256, 0, stream>>>(T3,T4,Wh,Wl, sc1,nullptr,nullptr,
              aobi, nullptr,nullptr, HP, Z,Z, 0.f);                         // ao_out
    k_add_ln<<<BN, blk256, 0, stream>>>(sc1, cur, g1i, b1i, sc2);           // attn -> sc2
    c_pad_split<<<gPad, blk256, 0, stream>>>(sc2, T1, T2);
    c_w_split<<<gW, blk256, 0, stream>>>(iwi, Wh, Wl);
    k_mfma3<1,3,1,2><<<gSm, blk256, 0, stream>>>(T1,T2,Wh,Wl, sc1,nullptr,nullptr,
              ibi, nullptr,nullptr, HP, Z,Z, 0.f);                          // gelu(inter)
    c_pad_split<<<gPad, blk256, 0, stream>>>(sc1, T3, T4);
    c_w_split<<<gW, blk256, 0, stream>>>(owi, Wh, Wl);
    k_mfma3<0,3,1,2><<<gSm, blk256, 0, stream>>>(T3,T4,Wh,Wl, cur,nullptr,nullptr,
              obi, nullptr,nullptr, HP, Z,Z, 0.f);                          // ow_out -> cur
    k_add_ln<<<BN, blk256, 0, stream>>>(cur, sc2, g2i, b2i, cur);           // bert out

    // ================= GCN on fo =================
    c_pad_split<<<gPad, blk256, 0, stream>>>(fo, T1, T2);
    c_w_split<<<gW, blk256, 0, stream>>>(gcn_w, Wh, Wl);
    k_mfma3<0,3,1,2><<<gSm, blk256, 0, stream>>>(T1,T2,Wh,Wl, sc1,nullptr,nullptr,
              nullptr, nullptr,nullptr, HP, Z,Z, 0.f);                      // teout
    c_padT_split<<<gPadT, bT, 0, stream>>>(sc1, T3, T4);                    // teout^T pair
    c_cvt1024<<<gNNel, blk256, 0, stream>>>(out_adj, adjb);                 // adj bf16 exact
    k_mfma3sk<5,2><<<gSK, blk256, 0, stream>>>(adjb,nullptr,T3,T4,
              fo, denom,nullptr,nullptr, Nd, sNN,sT);                       // fo += relu(./denom)

    // ================= self-alignment =================
    c_pad_split<<<gPad, blk256, 0, stream>>>(cur, T1, T2);
    c_w_split<<<gW, blk256, 0, stream>>>(mut_w, Wh, Wl);
    k_mfma3<2,3,1,2><<<gSm, blk256, 0, stream>>>(T1,T2,Wh,Wl, nullptr,T5,T6,
              nullptr, nullptr,nullptr, HP, Z,Z, 0.f);                      // mm pair
    c_pad_split<<<gPad, blk256, 0, stream>>>(fo, T1, T2);                   // fo pad pair
    k_mfma3<4,3,1,4><<<gNT, blk256, 0, stream>>>(T5,T6,T1,T2, S,nullptr,nullptr,
              nullptr, nullptr,maskf, HP, sNT,sNT, 0.f);                    // logits -> S
    k_colstats<<<dim3(Nd/64, Bd), dim3(1024), 0, stream>>>(S, cmaxv, csumv);
    k_rowstats<<<BN, blk256, 0, stream>>>(S, rmaxv, rsumv);
    c_prow_split<<<gNNel, blk256, 0, stream>>>(S, rmaxv, rsumv, Ph, Pl);    // p_row pair
    c_padT_split<<<gPadT, bT, 0, stream>>>(fo, T1, T2);                     // output^T pair
    k_mfma3sk<6,3><<<gSK, blk256, 0, stream>>>(Ph,Pl,T1,T2,
              sc1, nullptr,maskf,cur, Nd, sNN,sT);                          // new_outs -> sc1
    c_pcolT_split<<<gPcolT, bT, 0, stream>>>(S, cmaxv, csumv, Ph, Pl);      // p_col^T pair
    c_padT_split<<<gPadT, bT, 0, stream>>>(cur, T3, T4);                    // outs^T pair (old)
    k_mfma3sk<7,3><<<gSK, blk256, 0, stream>>>(Ph,Pl,T3,T4,
              fo, nullptr,maskf,nullptr, Nd, sNN,sT);                       // fo update

    float* t = cur; cur = sc1; sc1 = t;   // outs = new_outs
  }

  k_store<<<gBNH, blk256, 0, stream>>>(cur, out_outs);
}

// Round 13
// 1881.911 us; speedup vs baseline: 1.2714x; 1.2714x over previous
//
#include <hip/hip_runtime.h>
#include <hip/hip_bf16.h>
#include <math.h>

// Problem constants
#define Bd 8
#define Nd 1024
#define Hd 200
#define HP 224                      // Hd padded to multiple of 32
#define BN (Bd*Nd)                  // 8192
#define SZ_BNH ((size_t)BN*Hd)      // 1,638,400
#define SZ_BNN ((size_t)BN*Nd)      // 8,388,608
#define SZ_PAD ((size_t)BN*HP)      // 1,835,008

typedef __hip_bfloat16 bf16;
typedef __attribute__((ext_vector_type(8))) short bf16x8;   // 8 bf16 = 4 VGPRs (A/B frag)
typedef __attribute__((ext_vector_type(4))) float f32x4;    // C/D frag

__device__ __forceinline__ float bf2f(bf16 v){ return __bfloat162float(v); }
__device__ __forceinline__ bf16 f2bf(float v){ return __float2bfloat16(v); }

#define MFMA16(a,b,c) __builtin_amdgcn_mfma_f32_16x16x32_bf16((a),(b),(c),0,0,0)

// ============================ prep (fp32) ============================
__global__ void k_prep_masks(const float* __restrict__ tm, float* __restrict__ maskf,
                             float* __restrict__ maskadd){
  int i = blockIdx.x*256 + threadIdx.x;
  if (i < BN){ float m = tm[i]; maskf[i] = m; maskadd[i] = (1.f - m) * -10000.f; }
}

__global__ void k_prep_adj(const float* __restrict__ a1, const float* __restrict__ a2,
                           float* __restrict__ adj_out, float* __restrict__ denom){
  int r = blockIdx.x;
  const size_t base = (size_t)r * Nd;
  int t = threadIdx.x;
  float s = 0.f;
  for (int m = t; m < Nd; m += 256){
    float a = a1[base+m] + a2[base+m];
    a = a >= 1.f ? 1.f : a;
    adj_out[base+m] = a;
    s += a;
  }
  __shared__ float red[256];
  red[t] = s; __syncthreads();
  for (int st = 128; st > 0; st >>= 1){ if (t < st) red[t] += red[t+st]; __syncthreads(); }
  if (t == 0) denom[r] = red[0] + 1e-07f;
}

__global__ void k_copy2(const float* __restrict__ x, float* __restrict__ o1,
                        float* __restrict__ o2){
  size_t i = (size_t)blockIdx.x*256 + threadIdx.x;
  if (i < SZ_BNH){ float v = x[i]; o1[i] = v; o2[i] = v; }
}

// ============================ split conversions ============================
__global__ void c_pad_split(const float* __restrict__ X, bf16* __restrict__ Oh,
                            bf16* __restrict__ Ol){
  size_t i = (size_t)blockIdx.x*256 + threadIdx.x;
  if (i >= SZ_PAD) return;
  int c = (int)(i % HP); size_t r = i / HP;
  float v = (c < Hd) ? X[r*Hd + c] : 0.f;
  bf16 h = f2bf(v);
  Oh[i] = h; Ol[i] = f2bf(v - bf2f(h));
}

__global__ void c_padT_split(const float* __restrict__ X, bf16* __restrict__ Oh,
                             bf16* __restrict__ Ol){
  __shared__ float t[32][33];
  int b = blockIdx.z, m0 = blockIdx.x*32, d0 = blockIdx.y*32;
  int tx = threadIdx.x, ty = threadIdx.y;          // block (32,8)
  for (int i = ty; i < 32; i += 8){
    int d = d0 + tx;
    t[i][tx] = (d < Hd) ? X[((size_t)b*Nd + m0+i)*Hd + d] : 0.f;
  }
  __syncthreads();
  for (int i = ty; i < 32; i += 8){
    size_t idx = (size_t)b*HP*Nd + (size_t)(d0+i)*Nd + m0 + tx;
    float v = t[tx][i];
    bf16 h = f2bf(v);
    Oh[idx] = h; Ol[idx] = f2bf(v - bf2f(h));
  }
}

__global__ void c_w_split(const float* __restrict__ W, bf16* __restrict__ Oh,
                          bf16* __restrict__ Ol){
  int i = blockIdx.x*256 + threadIdx.x;
  if (i >= HP*HP) return;
  int n = i / HP, k = i % HP;
  float v = (n < Hd && k < Hd) ? W[k*Hd + n] : 0.f;
  bf16 h = f2bf(v);
  Oh[i] = h; Ol[i] = f2bf(v - bf2f(h));
}

__global__ void c_cvt1024(const float* __restrict__ X, bf16* __restrict__ O){
  size_t i = (size_t)blockIdx.x*256 + threadIdx.x;
  if (i < SZ_BNN) O[i] = f2bf(X[i]);
}

__global__ void c_pcolT_split(const float* __restrict__ S, const float* __restrict__ cmax,
                              const float* __restrict__ csum, bf16* __restrict__ Ph,
                              bf16* __restrict__ Pl){
  __shared__ float t[32][33];
  int b = blockIdx.z, n0 = blockIdx.x*32, m0 = blockIdx.y*32;
  int tx = threadIdx.x, ty = threadIdx.y;          // block (32,8)
  for (int i = ty; i < 32; i += 8)
    t[i][tx] = S[(size_t)b*Nd*Nd + (size_t)(n0+i)*Nd + m0 + tx];
  __syncthreads();
  for (int i = ty; i < 32; i += 8){
    int m = m0 + i;
    float cm = cmax[b*Nd + m], ci = 1.f / csum[b*Nd + m];
    float p = expf(t[tx][i] - cm) * ci;
    size_t idx = (size_t)b*Nd*Nd + (size_t)m*Nd + n0 + tx;
    bf16 h = f2bf(p);
    Ph[idx] = h; Pl[idx] = f2bf(p - bf2f(h));
  }
}

// ============================ fused row softmax ============================
// One block per row; row cached in LDS (4 KB); stats + prob write in ONE pass
// over S. Math identical to the old k_rowstats + c_prow(_split) pair:
// mx = max(row), sum = sum exp(row-mx) (same tree order), p = expf(s-mx)*(1/sum).
// SPLIT=0: single-bf16 P (attention).  SPLIT=1: Dekker pair (alignment).
template<int SPLIT>
__global__ __launch_bounds__(256)
void k_rowsoftmax(const float* __restrict__ S, bf16* __restrict__ Ph,
                  bf16* __restrict__ Pl){
  __shared__ float row[Nd];
  __shared__ float red[256];
  size_t r = blockIdx.x;
  const float* src = S + r*Nd;
  int t = threadIdx.x;
  float mx = -3.4e38f;
  for (int i = t; i < Nd; i += 256){ float v = src[i]; row[i] = v; mx = fmaxf(mx, v); }
  red[t] = mx; __syncthreads();
  for (int s = 128; s > 0; s >>= 1){ if (t < s) red[t] = fmaxf(red[t], red[t+s]); __syncthreads(); }
  mx = red[0]; __syncthreads();
  float sum = 0.f;
  for (int i = t; i < Nd; i += 256) sum += expf(row[i] - mx);
  red[t] = sum; __syncthreads();
  for (int s = 128; s > 0; s >>= 1){ if (t < s) red[t] += red[t+s]; __syncthreads(); }
  float inv = 1.f / red[0];
  for (int i = t; i < Nd; i += 256){
    float p = expf(row[i] - mx) * inv;
    bf16 h = f2bf(p);
    Ph[r*Nd + i] = h;
    if (SPLIT) Pl[r*Nd + i] = f2bf(p - bf2f(h));
  }
}

// Single-pass online column softmax stats. 1024 threads: 64 cols x 16 row-groups.
__global__ __launch_bounds__(1024)
void k_colstats(const float* __restrict__ S, float* __restrict__ cmax,
                float* __restrict__ csum){
  int b = blockIdx.y;
  int tx = threadIdx.x & 63, ty = threadIdx.x >> 6;   // ty in 0..15
  int m = blockIdx.x*64 + tx;
  const float* Sbp = S + (size_t)b*Nd*Nd + m;
  float mx = -3.4e38f, sm = 0.f;
  for (int n = ty; n < Nd; n += 16){
    float x = Sbp[(size_t)n*Nd];
    if (x > mx){ sm = sm * expf(mx - x) + 1.f; mx = x; }
    else        sm += expf(x - mx);
  }
  __shared__ float smx[16][64], ssm[16][64];
  smx[ty][tx] = mx; ssm[ty][tx] = sm;
  __syncthreads();
  for (int st = 8; st > 0; st >>= 1){
    if (ty < st){
      float m1 = smx[ty][tx],    s1 = ssm[ty][tx];
      float m2 = smx[ty+st][tx], s2 = ssm[ty+st][tx];
      float M = fmaxf(m1, m2);
      smx[ty][tx] = M;
      ssm[ty][tx] = s1*expf(m1 - M) + s2*expf(m2 - M);
    }
    __syncthreads();
  }
  if (ty == 0){ cmax[b*Nd + m] = smx[0][tx]; csum[b*Nd + m] = ssm[0][tx]; }
}

// ============================ residual + layernorm ============================
__global__ void k_add_ln(const float* __restrict__ X, const float* __restrict__ R,
                         const float* __restrict__ g, const float* __restrict__ bb,
                         float* __restrict__ Y){
  int r = blockIdx.x, t = threadIdx.x;
  __shared__ float red[256];
  bool act = t < Hd;
  float v = 0.f;
  if (act) v = X[(size_t)r*Hd + t] + R[(size_t)r*Hd + t];
  red[t] = act ? v : 0.f; __syncthreads();
  for (int s = 128; s > 0; s >>= 1){ if (t < s) red[t] += red[t+s]; __syncthreads(); }
  float mu = red[0] * (1.f/Hd); __syncthreads();
  float d = act ? (v - mu) : 0.f;
  red[t] = d*d; __syncthreads();
  for (int s = 128; s > 0; s >>= 1){ if (t < s) red[t] += red[t+s]; __syncthreads(); }
  float var = red[0] * (1.f/Hd);
  if (act){
    float rs = 1.f / sqrtf(var + 1e-20f);
    Y[(size_t)r*Hd + t] = (v - mu) * rs * g[t] + bb[t];
  }
}

__global__ void k_store(const float* __restrict__ X, float* __restrict__ O){
  size_t i = (size_t)blockIdx.x*256 + threadIdx.x;
  if (i < SZ_BNH) O[i] = X[i];
}

// ============================ split-precision MFMA GEMM (no split-K) ============
// D[m][n] = sum_k A[m][k]*B[n][k] (NT), Dekker split. RI row-tiles x 4 col-tiles/wave.
// Block = 4 waves stacked in M. EPI: 0 fp32 Y=acc+bias  1 +gelu  2 split-bf16pad out
// 3 S=acc*scale+maskadd[col]  4 S=acc+pairmask
template<int EPI, int TERMS, int RI>
__global__ __launch_bounds__(256)
void k_mfma3(const bf16* __restrict__ Ah, const bf16* __restrict__ Al,
             const bf16* __restrict__ Bh, const bf16* __restrict__ Bl,
             float* __restrict__ Y, bf16* __restrict__ Ybh, bf16* __restrict__ Ybl,
             const float* __restrict__ bias, const float* __restrict__ e0,
             const float* __restrict__ e1,
             int Kp, size_t sAb, size_t sBb, float scale)
{
  int b = blockIdx.z;
  int wave = threadIdx.x >> 6, lane = threadIdx.x & 63;
  int r0 = (blockIdx.y*4 + wave)*(RI*16);
  int c0 = blockIdx.x*64;
  int lm = lane & 15, lq = lane >> 4;
  size_t a0 = (size_t)b*sAb + (size_t)(r0+lm)*Kp + lq*8;
  size_t bo = (size_t)b*sBb + (size_t)(c0+lm)*Kp + lq*8;

  f32x4 acc[RI][4] = {};
  for (int k = 0; k < Kp; k += 32){
    bf16x8 ah[RI], bh[4], bl[4];
    #pragma unroll
    for (int i = 0; i < RI; i++) ah[i] = *(const bf16x8*)(Ah + a0 + (size_t)(i*16)*Kp + k);
    #pragma unroll
    for (int j = 0; j < 4; j++){
      bh[j] = *(const bf16x8*)(Bh + bo + (size_t)(j*16)*Kp + k);
      bl[j] = *(const bf16x8*)(Bl + bo + (size_t)(j*16)*Kp + k);
    }
    #pragma unroll
    for (int i = 0; i < RI; i++)
      #pragma unroll
      for (int j = 0; j < 4; j++) acc[i][j] = MFMA16(ah[i], bh[j], acc[i][j]);
    #pragma unroll
    for (int i = 0; i < RI; i++)
      #pragma unroll
      for (int j = 0; j < 4; j++) acc[i][j] = MFMA16(ah[i], bl[j], acc[i][j]);
    if (TERMS >= 3){
      bf16x8 al[RI];
      #pragma unroll
      for (int i = 0; i < RI; i++) al[i] = *(const bf16x8*)(Al + a0 + (size_t)(i*16)*Kp + k);
      #pragma unroll
      for (int i = 0; i < RI; i++)
        #pragma unroll
        for (int j = 0; j < 4; j++) acc[i][j] = MFMA16(al[i], bh[j], acc[i][j]);
    }
  }

  #pragma unroll
  for (int i = 0; i < RI; i++){
    #pragma unroll
    for (int j = 0; j < 4; j++){
      int col = c0 + j*16 + lm;
      int rbase = r0 + i*16 + lq*4;
      #pragma unroll
      for (int r = 0; r < 4; r++){
        int row = rbase + r;
        size_t rowg = (size_t)b*Nd + row;
        float v = acc[i][j][r];
        if (EPI == 0 || EPI == 1){
          if (col < Hd){
            v += bias ? bias[col] : 0.f;
            if (EPI == 1) v = 0.5f*v*(1.f + erff(v*0.7071067811865476f));
            Y[rowg*Hd + col] = v;
          }
        } else if (EPI == 2){
          if (col < HP){
            float o = (col < Hd) ? v + (bias ? bias[col] : 0.f) : 0.f;
            bf16 h = f2bf(o);
            Ybh[rowg*HP + col] = h;
            Ybl[rowg*HP + col] = f2bf(o - bf2f(h));
          }
        } else if (EPI == 3){
          Y[rowg*Nd + col] = v*scale + e0[b*Nd + col];
        } else if (EPI == 4){
          Y[rowg*Nd + col] = v + (1.f - e1[b*Nd+row]*e1[b*Nd+col])*(-10000.f);
        }
      }
    }
  }
}

// ============================ split-K=4 MFMA GEMM (K=1024 mixes) ================
// Block = one 32x64 tile; 4 waves each own a K/4 chunk; LDS combine (fixed order
// red[0]+red[1]+red[2]+red[3]); wave (iw,j0) epilogues its slice.
// XCD swizzle: blockIdx.x = row-tile (32), blockIdx.y = col-group (4) — the 4
// col-group blocks sharing an A-tile are stride-32 apart in linear block ID,
// landing on the SAME XCD (32 % 8 == 0) so A re-reads hit local L2.
// EPI: 0 Y=acc  5 Y+=relu(acc/denom[row])  6 Y=acc*maskf[row]+R  7 Y=acc*maskf[row]+Y
template<int EPI, int TERMS>
__global__ __launch_bounds__(256)
void k_mfma3sk(const bf16* __restrict__ Ah, const bf16* __restrict__ Al,
               const bf16* __restrict__ Bh, const bf16* __restrict__ Bl,
               float* __restrict__ Y, const float* __restrict__ e0,
               const float* __restrict__ e1, const float* __restrict__ R,
               int Kp, size_t sAb, size_t sBb)
{
  __shared__ float red[4][64][33];
  int b = blockIdx.z;
  int wave = threadIdx.x >> 6, lane = threadIdx.x & 63;
  int r0 = blockIdx.x*32;
  int c0 = blockIdx.y*64;
  int lm = lane & 15, lq = lane >> 4;
  size_t a0 = (size_t)b*sAb + (size_t)(r0+lm)*Kp + lq*8;
  size_t bo = (size_t)b*sBb + (size_t)(c0+lm)*Kp + lq*8;
  int kb = wave*(Kp>>2), ke = kb + (Kp>>2);

  f32x4 acc[2][4] = {};
  for (int k = kb; k < ke; k += 32){
    bf16x8 ah[2], bh[4], bl[4];
    #pragma unroll
    for (int i = 0; i < 2; i++) ah[i] = *(const bf16x8*)(Ah + a0 + (size_t)(i*16)*Kp + k);
    #pragma unroll
    for (int j = 0; j < 4; j++){
      bh[j] = *(const bf16x8*)(Bh + bo + (size_t)(j*16)*Kp + k);
      bl[j] = *(const bf16x8*)(Bl + bo + (size_t)(j*16)*Kp + k);
    }
    #pragma unroll
    for (int i = 0; i < 2; i++)
      #pragma unroll
      for (int j = 0; j < 4; j++) acc[i][j] = MFMA16(ah[i], bh[j], acc[i][j]);
    #pragma unroll
    for (int i = 0; i < 2; i++)
      #pragma unroll
      for (int j = 0; j < 4; j++) acc[i][j] = MFMA16(ah[i], bl[j], acc[i][j]);
    if (TERMS >= 3){
      bf16x8 al[2];
      #pragma unroll
      for (int i = 0; i < 2; i++) al[i] = *(const bf16x8*)(Al + a0 + (size_t)(i*16)*Kp + k);
      #pragma unroll
      for (int i = 0; i < 2; i++)
        #pragma unroll
        for (int j = 0; j < 4; j++) acc[i][j] = MFMA16(al[i], bh[j], acc[i][j]);
    }
  }

  #pragma unroll
  for (int i = 0; i < 2; i++)
    #pragma unroll
    for (int j = 0; j < 4; j++)
      #pragma unroll
      for (int r = 0; r < 4; r++)
        red[wave][lane][i*16 + j*4 + r] = acc[i][j][r];
  __syncthreads();

  int iw = wave >> 1, j0 = (wave & 1)*2;
  #pragma unroll
  for (int jj = 0; jj < 2; jj++){
    int j = j0 + jj;
    int col = c0 + j*16 + lm;
    #pragma unroll
    for (int r = 0; r < 4; r++){
      int f = iw*16 + j*4 + r;
      float v = red[0][lane][f] + red[1][lane][f] + red[2][lane][f] + red[3][lane][f];
      int row = r0 + iw*16 + lq*4 + r;
      size_t rowg = (size_t)b*Nd + row;
      if (EPI == 0){
        if (col < Hd) Y[rowg*Hd + col] = v;
      } else if (EPI == 5){
        if (col < Hd){
          float u = v / e0[b*Nd+row]; u = u > 0.f ? u : 0.f;
          Y[rowg*Hd + col] += u;
        }
      } else if (EPI == 6){
        if (col < Hd) Y[rowg*Hd+col] = v*e1[b*Nd+row] + R[rowg*Hd+col];
      } else if (EPI == 7){
        if (col < Hd) Y[rowg*Hd+col] = v*e1[b*Nd+row] + Y[rowg*Hd+col];
      }
    }
  }
}

// ============================ host launch ============================
static inline char* carve(char*& p, size_t bytes){
  char* r = p;
  p += (bytes + 511) & ~(size_t)511;
  return r;
}

extern "C" void kernel_launch(void* const* d_in, const int* in_sizes, int n_in,
                              void* d_out, int out_size, void* d_ws, size_t ws_size,
                              hipStream_t stream){
  (void)in_sizes; (void)n_in; (void)out_size; (void)ws_size;
  const float* text     = (const float*)d_in[0];
  const float* adj1     = (const float*)d_in[1];
  const float* adj2     = (const float*)d_in[2];
  const float* textmask = (const float*)d_in[5];
  const float* gcn_w    = (const float*)d_in[6];
  const float* mut_w    = (const float*)d_in[7];
  const float* qw = (const float*)d_in[8],  *qb = (const float*)d_in[9];
  const float* kw = (const float*)d_in[10], *kb = (const float*)d_in[11];
  const float* vw = (const float*)d_in[12], *vb = (const float*)d_in[13];
  const float* aow= (const float*)d_in[14], *aob= (const float*)d_in[15];
  const float* g1 = (const float*)d_in[16], *b1 = (const float*)d_in[17];
  const float* iw = (const float*)d_in[18], *ib = (const float*)d_in[19];
  const float* ow = (const float*)d_in[20], *ob = (const float*)d_in[21];
  const float* g2 = (const float*)d_in[22], *b2 = (const float*)d_in[23];

  float* out_outs = (float*)d_out;
  float* out_adj  = out_outs + SZ_BNH;

  // ---- workspace carve (~109 MB). out_outs doubles as fp32 scratch sc2. ----
  char* p = (char*)d_ws;
  float* cur  = (float*)carve(p, SZ_BNH*4);
  float* sc1  = (float*)carve(p, SZ_BNH*4);
  float* fo   = (float*)carve(p, SZ_BNH*4);
  float* S    = (float*)carve(p, SZ_BNN*4);           // fp32 scores / logits
  bf16*  Rb   = (bf16*)carve(p, SZ_BNN*2*2);          // big bf16 region (33.6 MB)
  bf16*  T1   = (bf16*)carve(p, SZ_PAD*2);
  bf16*  T2   = (bf16*)carve(p, SZ_PAD*2);
  bf16*  T3   = (bf16*)carve(p, SZ_PAD*2);
  bf16*  T4   = (bf16*)carve(p, SZ_PAD*2);
  bf16*  T5   = (bf16*)carve(p, SZ_PAD*2);
  bf16*  T6   = (bf16*)carve(p, SZ_PAD*2);
  bf16*  Wh   = (bf16*)carve(p, (size_t)HP*HP*2);
  bf16*  Wl   = (bf16*)carve(p, (size_t)HP*HP*2);
  float* denom   = (float*)carve(p, BN*4);
  float* maskf   = (float*)carve(p, BN*4);
  float* maskadd = (float*)carve(p, BN*4);
  float* cmaxv   = (float*)carve(p, BN*4);
  float* csumv   = (float*)carve(p, BN*4);

  float* sc2 = out_outs;          // fp32 scratch; overwritten by final k_store
  bf16* attnP = Rb;               // phases: attnP -> adjb -> p_row Ph/Pl -> p_col Ph/Pl
  bf16* adjb  = Rb;
  bf16* Ph    = Rb;
  bf16* Pl    = Rb + SZ_BNN;

  const size_t sNT = (size_t)Nd*HP;     // batch stride, [1024][224]
  const size_t sT  = (size_t)HP*Nd;     // batch stride, [224][1024]
  const size_t sNN = (size_t)Nd*Nd;     // batch stride, [1024][1024]

  dim3 blk256(256);
  dim3 gPad((unsigned)((SZ_PAD+255)/256));
  dim3 gPadT(32, 7, Bd), bT(32, 8);
  dim3 gPcolT(32, 32, Bd);
  dim3 gW((HP*HP+255)/256);
  dim3 gNNel((unsigned)((SZ_BNN+255)/256));
  dim3 gBNH((unsigned)((SZ_BNH+255)/256));
  // GEMM grids (round-11-bench proven configuration)
  dim3 gSm(4, 128, 1);       // small GEMM: 16x64/wave (RI=1), 8192 rows, K=HP
  dim3 gNT(16, 8, Bd);       // scores/logits: 32x64/wave (RI=2), K=HP
  dim3 gSK(32, 4, Bd);       // split-K=4 mixes: 32-row blocks, x=row-tile, y=col-group
  const float inv_sqrt_h = 0.07071067811865475f;  // 1/sqrt(200)
  const size_t Z = 0;

  k_prep_masks<<<(BN+255)/256, blk256, 0, stream>>>(textmask, maskf, maskadd);
  k_prep_adj<<<BN, blk256, 0, stream>>>(adj1, adj2, out_adj, denom);
  k_copy2<<<gBNH, blk256, 0, stream>>>(text, cur, fo);

  for (int i = 0; i < 3; i++){
    const float *qwi = qw + i*Hd*Hd, *qbi = qb + i*Hd;
    const float *kwi = kw + i*Hd*Hd, *kbi = kb + i*Hd;
    const float *vwi = vw + i*Hd*Hd, *vbi = vb + i*Hd;
    const float *aowi= aow+ i*Hd*Hd, *aobi= aob+ i*Hd;
    const float *g1i = g1 + i*Hd,    *b1i = b1 + i*Hd;
    const float *iwi = iw + i*Hd*Hd, *ibi = ib + i*Hd;
    const float *owi = ow + i*Hd*Hd, *obi = ob + i*Hd;
    const float *g2i = g2 + i*Hd,    *b2i = b2 + i*Hd;

    // ================= BERT layer: cur -> cur =================
    c_pad_split<<<gPad, blk256, 0, stream>>>(cur, T1, T2);                  // cur pair
    c_w_split<<<gW, blk256, 0, stream>>>(qwi, Wh, Wl);
    k_mfma3<2,3,1><<<gSm, blk256, 0, stream>>>(T1,T2,Wh,Wl, nullptr,T3,T4,
              qbi, nullptr,nullptr, HP, Z,Z, 0.f);                          // Q pair
    c_w_split<<<gW, blk256, 0, stream>>>(kwi, Wh, Wl);
    k_mfma3<2,3,1><<<gSm, blk256, 0, stream>>>(T1,T2,Wh,Wl, nullptr,T5,T6,
              kbi, nullptr,nullptr, HP, Z,Z, 0.f);                          // K pair
    k_mfma3<3,3,2><<<gNT, blk256, 0, stream>>>(T3,T4,T5,T6, S,nullptr,nullptr,
              nullptr, maskadd,nullptr, HP, sNT,sNT, inv_sqrt_h);           // scores
    c_w_split<<<gW, blk256, 0, stream>>>(vwi, Wh, Wl);
    k_mfma3<0,3,1><<<gSm, blk256, 0, stream>>>(T1,T2,Wh,Wl, sc1,nullptr,nullptr,
              vbi, nullptr,nullptr, HP, Z,Z, 0.f);                          // V fp32
    k_rowsoftmax<0><<<BN, blk256, 0, stream>>>(S, attnP, nullptr);          // attn probs (fused)
    c_padT_split<<<gPadT, bT, 0, stream>>>(sc1, T1, T2);                    // V^T pair
    k_mfma3sk<0,2><<<gSK, blk256, 0, stream>>>(attnP,nullptr,T1,T2,
              sc2, nullptr,nullptr,nullptr, Nd, sNN,sT);                    // ctx
    c_pad_split<<<gPad, blk256, 0, stream>>>(sc2, T3, T4);
    c_w_split<<<gW, blk256, 0, stream>>>(aowi, Wh, Wl);
    k_mfma3<0,3,1><<<gSm, blk256, 0, stream>>>(T3,T4,Wh,Wl, sc1,nullptr,nullptr,
              aobi, nullptr,nullptr, HP, Z,Z, 0.f);                         // ao_out
    k_add_ln<<<BN, blk256, 0, stream>>>(sc1, cur, g1i, b1i, sc2);           // attn -> sc2
    c_pad_split<<<gPad, blk256, 0, stream>>>(sc2, T1, T2);
    c_w_split<<<gW, blk256, 0, stream>>>(iwi, Wh, Wl);
    k_mfma3<1,3,1><<<gSm, blk256, 0, stream>>>(T1,T2,Wh,Wl, sc1,nullptr,nullptr,
              ibi, nullptr,nullptr, HP, Z,Z, 0.f);                          // gelu(inter)
    c_pad_split<<<gPad, blk256, 0, stream>>>(sc1, T3, T4);
    c_w_split<<<gW, blk256, 0, stream>>>(owi, Wh, Wl);
    k_mfma3<0,3,1><<<gSm, blk256, 0, stream>>>(T3,T4,Wh,Wl, cur,nullptr,nullptr,
              obi, nullptr,nullptr, HP, Z,Z, 0.f);                          // ow_out -> cur
    k_add_ln<<<BN, blk256, 0, stream>>>(cur, sc2, g2i, b2i, cur);           // bert out

    // ================= GCN on fo =================
    c_pad_split<<<gPad, blk256, 0, stream>>>(fo, T1, T2);
    c_w_split<<<gW, blk256, 0, stream>>>(gcn_w, Wh, Wl);
    k_mfma3<0,3,1><<<gSm, blk256, 0, stream>>>(T1,T2,Wh,Wl, sc1,nullptr,nullptr,
              nullptr, nullptr,nullptr, HP, Z,Z, 0.f);                      // teout
    c_padT_split<<<gPadT, bT, 0, stream>>>(sc1, T3, T4);                    // teout^T pair
    c_cvt1024<<<gNNel, blk256, 0, stream>>>(out_adj, adjb);                 // adj bf16 exact
    k_mfma3sk<5,2><<<gSK, blk256, 0, stream>>>(adjb,nullptr,T3,T4,
              fo, denom,nullptr,nullptr, Nd, sNN,sT);                       // fo += relu(./denom)

    // ================= self-alignment =================
    c_pad_split<<<gPad, blk256, 0, stream>>>(cur, T1, T2);
    c_w_split<<<gW, blk256, 0, stream>>>(mut_w, Wh, Wl);
    k_mfma3<2,3,1><<<gSm, blk256, 0, stream>>>(T1,T2,Wh,Wl, nullptr,T5,T6,
              nullptr, nullptr,nullptr, HP, Z,Z, 0.f);                      // mm pair
    c_pad_split<<<gPad, blk256, 0, stream>>>(fo, T1, T2);                   // fo pad pair
    k_mfma3<4,3,2><<<gNT, blk256, 0, stream>>>(T5,T6,T1,T2, S,nullptr,nullptr,
              nullptr, nullptr,maskf, HP, sNT,sNT, 0.f);                    // logits -> S
    k_colstats<<<dim3(Nd/64, Bd), dim3(1024), 0, stream>>>(S, cmaxv, csumv);
    k_rowsoftmax<1><<<BN, blk256, 0, stream>>>(S, Ph, Pl);                  // p_row pair (fused)
    c_padT_split<<<gPadT, bT, 0, stream>>>(fo, T1, T2);                     // output^T pair
    k_mfma3sk<6,3><<<gSK, blk256, 0, stream>>>(Ph,Pl,T1,T2,
              sc1, nullptr,maskf,cur, Nd, sNN,sT);                          // new_outs -> sc1
    c_pcolT_split<<<gPcolT, bT, 0, stream>>>(S, cmaxv, csumv, Ph, Pl);      // p_col^T pair
    c_padT_split<<<gPadT, bT, 0, stream>>>(cur, T3, T4);                    // outs^T pair (old)
    k_mfma3sk<7,3><<<gSK, blk256, 0, stream>>>(Ph,Pl,T3,T4,
              fo, nullptr,maskf,nullptr, Nd, sNN,sT);                       // fo update

    float* t = cur; cur = sc1; sc1 = t;   // outs = new_outs
  }

  k_store<<<gBNH, blk256, 0, stream>>>(cur, out_outs);
}